// Round 1
// baseline (11060.372 us; speedup 1.0000x reference)
//
#include <hip/hip_runtime.h>

// ---------------- types / helpers ----------------
typedef unsigned short u16;
typedef __bf16 bf16x8 __attribute__((ext_vector_type(8)));
typedef float f32x4 __attribute__((ext_vector_type(4)));
typedef u16 u16x8 __attribute__((ext_vector_type(8)));

static_assert(sizeof(bf16x8) == 16, "bf16x8 must be 16B");

#define DEV static __device__ __forceinline__

DEV u16 f2bf(float f) {
  unsigned u = __float_as_uint(f);
  u += 0x7FFFu + ((u >> 16) & 1u);   // RNE; inputs are well-behaved (no NaN/Inf)
  return (u16)(u >> 16);
}
DEV f32x4 mfma16(bf16x8 a, bf16x8 b, f32x4 c) {
  return __builtin_amdgcn_mfma_f32_16x16x32_bf16(a, b, c, 0, 0, 0);
}
DEV bf16x8 ldfrag(const u16* p) { return *reinterpret_cast<const bf16x8*>(p); }
DEV float sigf(float x) { return 1.0f / (1.0f + __expf(-x)); }

// dims
#define Bn 32
#define Sn 128
#define Td 127
#define En 512
#define Hn 1024
#define G4 4096
#define Vn 32000

// ---------------- f32 -> bf16 convert ----------------
__global__ __launch_bounds__(256) void cvt_bf16_kernel(const float* __restrict__ in,
                                                       u16* __restrict__ out, int n8) {
  int gid = blockIdx.x * 256 + threadIdx.x;
  if (gid >= n8) return;
  const float4* ip = (const float4*)in + gid * 2;
  float4 x = ip[0], y = ip[1];
  u16x8 o;
  o[0] = f2bf(x.x); o[1] = f2bf(x.y); o[2] = f2bf(x.z); o[3] = f2bf(x.w);
  o[4] = f2bf(y.x); o[5] = f2bf(y.y); o[6] = f2bf(y.z); o[7] = f2bf(y.w);
  ((u16x8*)out)[gid] = o;
}

// ---------------- embedding gather (to bf16, (t*B+b, E) layout) ----------------
__global__ __launch_bounds__(256) void gather_embed_kernel(const int* __restrict__ idx, int ldidx,
                                                           const float* __restrict__ embed,
                                                           u16* __restrict__ outA, int nrows) {
  int gid = blockIdx.x * 256 + threadIdx.x;          // one thread = 8 elems
  int total = nrows * (En / 8);
  if (gid >= total) return;
  int r = gid / (En / 8);
  int ck = gid % (En / 8);
  int tcol = r / Bn, b = r % Bn;
  int tok = idx[b * ldidx + tcol];
  const float4* src = (const float4*)(embed + (size_t)tok * En + ck * 8);
  float4 x = src[0], y = src[1];
  u16x8 o;
  o[0] = f2bf(x.x); o[1] = f2bf(x.y); o[2] = f2bf(x.z); o[3] = f2bf(x.w);
  o[4] = f2bf(y.x); o[5] = f2bf(y.y); o[6] = f2bf(y.z); o[7] = f2bf(y.w);
  *(u16x8*)(outA + (size_t)r * En + ck * 8) = o;
}

// ---------------- big GEMM: C(M,N) = A(M,K) @ W(N,K)^T + bias0 + bias1 ----------------
// one wave per 16x16 tile, direct global loads (cache-served)
__global__ __launch_bounds__(256) void gemm_bias_kernel(const u16* __restrict__ A, int lda,
                                                        const u16* __restrict__ W, int ldw,
                                                        const float* __restrict__ bias0,
                                                        const float* __restrict__ bias1,
                                                        float* __restrict__ C, int ldc,
                                                        int Mtiles, int K) {
  int wid = (blockIdx.x * 256 + threadIdx.x) >> 6;
  int lane = threadIdx.x & 63;
  int mt = wid % Mtiles, nt = wid / Mtiles;
  int lrow = lane & 15, kgrp = lane >> 4;
  f32x4 acc = {};
  const u16* arow = A + (size_t)(mt * 16 + lrow) * lda;
  const u16* wrow = W + (size_t)(nt * 16 + lrow) * ldw;
  for (int k0 = kgrp * 8; k0 < K; k0 += 32) {
    bf16x8 a = ldfrag(arow + k0);
    bf16x8 b = ldfrag(wrow + k0);
    acc = mfma16(a, b, acc);
  }
  int col = nt * 16 + lrow;
  float bias = (bias0 ? bias0[col] : 0.f) + (bias1 ? bias1[col] : 0.f);
#pragma unroll
  for (int r = 0; r < 4; ++r) {
    int rrow = mt * 16 + kgrp * 4 + r;
    C[(size_t)rrow * ldc + col] = acc[r] + bias;
  }
}

// ---------------- encoder LSTM step ----------------
// grid 128 blocks: mt = blk&1 (batch half), ht = blk>>1 (h-column tile). 4 waves split K.
__global__ __launch_bounds__(256) void lstm_step_kernel(const float* __restrict__ premix_t,  // B x 4H
                                                        const u16* __restrict__ Whh,        // 4H x H
                                                        const u16* __restrict__ hb_in,      // B x H
                                                        float* __restrict__ h, float* __restrict__ c,
                                                        u16* __restrict__ hb_out,
                                                        u16* __restrict__ hs_b_t,   // B x H or null
                                                        float* __restrict__ hs_f_t) // B x H or null
{
  const int mt = blockIdx.x & 1;
  const int ht = blockIdx.x >> 1;
  const int wave = threadIdx.x >> 6;
  const int lane = threadIdx.x & 63;
  const int lrow = lane & 15, kgrp = lane >> 4;
  f32x4 acc[4] = {};
  const int kbase = wave * 256;
#pragma unroll 2
  for (int kk = 0; kk < 8; ++kk) {
    int k0 = kbase + kk * 32 + kgrp * 8;
    bf16x8 a = ldfrag(hb_in + (size_t)(mt * 16 + lrow) * Hn + k0);
#pragma unroll
    for (int g = 0; g < 4; ++g) {
      bf16x8 b = ldfrag(Whh + (size_t)(g * Hn + ht * 16 + lrow) * Hn + k0);
      acc[g] = mfma16(a, b, acc[g]);
    }
  }
  __shared__ float lds[4][4][16][16];
#pragma unroll
  for (int g = 0; g < 4; ++g)
#pragma unroll
    for (int r = 0; r < 4; ++r)
      lds[wave][g][kgrp * 4 + r][lrow] = acc[g][r];
  __syncthreads();
  // epilogue: 256 threads <-> 16x16 tile
  int row = threadIdx.x >> 4, col = threadIdx.x & 15;
  int brow = mt * 16 + row, hcol = ht * 16 + col;
  float gs[4];
#pragma unroll
  for (int g = 0; g < 4; ++g) {
    float s = lds[0][g][row][col] + lds[1][g][row][col] + lds[2][g][row][col] + lds[3][g][row][col];
    gs[g] = s + premix_t[(size_t)brow * G4 + g * Hn + hcol];
  }
  float cold = c[brow * Hn + hcol];
  float ig = sigf(gs[0]), fg = sigf(gs[1]), gg = tanhf(gs[2]), og = sigf(gs[3]);
  float cn = fg * cold + ig * gg;
  float hn = og * tanhf(cn);
  c[brow * Hn + hcol] = cn;
  h[brow * Hn + hcol] = hn;
  u16 hb = f2bf(hn);
  hb_out[brow * Hn + hcol] = hb;
  if (hs_b_t) hs_b_t[brow * Hn + hcol] = hb;
  if (hs_f_t) hs_f_t[brow * Hn + hcol] = hn;
}

// ---------------- decoder LSTM step (ctx@Wih_ctx^T + h@Whh^T + premix) ----------------
__global__ __launch_bounds__(256) void dec_step_kernel(const float* __restrict__ premix_t,
                                                       const u16* __restrict__ Wih_ctx, // ldw 1536
                                                       const u16* __restrict__ Whh,
                                                       const u16* __restrict__ ctx_b,
                                                       const u16* __restrict__ hb_in,
                                                       float* __restrict__ h, float* __restrict__ c,
                                                       u16* __restrict__ hb_out) {
  const int mt = blockIdx.x & 1;
  const int ht = blockIdx.x >> 1;
  const int wave = threadIdx.x >> 6;
  const int lane = threadIdx.x & 63;
  const int lrow = lane & 15, kgrp = lane >> 4;
  f32x4 acc[4] = {};
  const int kbase = wave * 256;
#pragma unroll 2
  for (int kk = 0; kk < 8; ++kk) {
    int k0 = kbase + kk * 32 + kgrp * 8;
    bf16x8 a = ldfrag(ctx_b + (size_t)(mt * 16 + lrow) * Hn + k0);
#pragma unroll
    for (int g = 0; g < 4; ++g) {
      bf16x8 b = ldfrag(Wih_ctx + (size_t)(g * Hn + ht * 16 + lrow) * 1536 + k0);
      acc[g] = mfma16(a, b, acc[g]);
    }
  }
#pragma unroll 2
  for (int kk = 0; kk < 8; ++kk) {
    int k0 = kbase + kk * 32 + kgrp * 8;
    bf16x8 a = ldfrag(hb_in + (size_t)(mt * 16 + lrow) * Hn + k0);
#pragma unroll
    for (int g = 0; g < 4; ++g) {
      bf16x8 b = ldfrag(Whh + (size_t)(g * Hn + ht * 16 + lrow) * Hn + k0);
      acc[g] = mfma16(a, b, acc[g]);
    }
  }
  __shared__ float lds[4][4][16][16];
#pragma unroll
  for (int g = 0; g < 4; ++g)
#pragma unroll
    for (int r = 0; r < 4; ++r)
      lds[wave][g][kgrp * 4 + r][lrow] = acc[g][r];
  __syncthreads();
  int row = threadIdx.x >> 4, col = threadIdx.x & 15;
  int brow = mt * 16 + row, hcol = ht * 16 + col;
  float gs[4];
#pragma unroll
  for (int g = 0; g < 4; ++g) {
    float s = lds[0][g][row][col] + lds[1][g][row][col] + lds[2][g][row][col] + lds[3][g][row][col];
    gs[g] = s + premix_t[(size_t)brow * G4 + g * Hn + hcol];
  }
  float cold = c[brow * Hn + hcol];
  float ig = sigf(gs[0]), fg = sigf(gs[1]), gg = tanhf(gs[2]), og = sigf(gs[3]);
  float cn = fg * cold + ig * gg;
  float hn = og * tanhf(cn);
  c[brow * Hn + hcol] = cn;
  h[brow * Hn + hcol] = hn;
  hb_out[brow * Hn + hcol] = f2bf(hn);
}

// ---------------- fc (out = h@fc_W^T + fc_b) fused with attention(t+1) ----------------
// blocks [0, nfc): fc, one wave = 32x16 tile. blocks [nfc, nfc+32): attention for b = blk-nfc.
__global__ __launch_bounds__(256) void fc_attn_kernel(const u16* __restrict__ hb,   // B x H bf16
                                                      const float* __restrict__ hf, // B x H f32
                                                      const u16* __restrict__ fcWb, // V x H bf16
                                                      const float* __restrict__ fcb,
                                                      float* __restrict__ out,
                                                      const float* __restrict__ enc_out, // S x B x H
                                                      float* __restrict__ ctx, u16* __restrict__ ctx_b,
                                                      int t, int nfc) {
  __shared__ float hsh[Hn];
  __shared__ float sc[Sn];
  __shared__ float cpart[4][Hn];
  const int wave = threadIdx.x >> 6;
  const int lane = threadIdx.x & 63;

  if ((int)blockIdx.x < nfc) {
    int nt = blockIdx.x * 4 + wave;            // 0..1999
    int lrow = lane & 15, kgrp = lane >> 4;
    f32x4 acc0 = {}, acc1 = {};
    const u16* wrow = fcWb + (size_t)(nt * 16 + lrow) * Hn;
#pragma unroll 4
    for (int kk = 0; kk < 32; ++kk) {
      int k0 = kk * 32 + kgrp * 8;
      bf16x8 a0 = ldfrag(hb + (size_t)lrow * Hn + k0);
      bf16x8 a1 = ldfrag(hb + (size_t)(16 + lrow) * Hn + k0);
      bf16x8 b = ldfrag(wrow + k0);
      acc0 = mfma16(a0, b, acc0);
      acc1 = mfma16(a1, b, acc1);
    }
    int v = nt * 16 + lrow;
    float bias = fcb[v];
#pragma unroll
    for (int r = 0; r < 4; ++r) {
      int b0 = kgrp * 4 + r;
      out[((size_t)b0 * Td + t) * Vn + v] = acc0[r] + bias;
      out[((size_t)(b0 + 16) * Td + t) * Vn + v] = acc1[r] + bias;
    }
    return;
  }

  // ---- attention for next step ----
  int bb = blockIdx.x - nfc;
  int tid = threadIdx.x;
  ((float4*)hsh)[tid] = ((const float4*)(hf + (size_t)bb * Hn))[tid];
  __syncthreads();
  // scores: wave w handles s = w*32..w*32+31; full-wave dot over 1024
  for (int i = 0; i < 32; ++i) {
    int s = wave * 32 + i;
    const float4* r4 = (const float4*)(enc_out + ((size_t)s * Bn + bb) * Hn) + lane * 4;
    const float4* h4 = (const float4*)hsh + lane * 4;
    float p = 0.f;
#pragma unroll
    for (int q = 0; q < 4; ++q) {
      float4 rv = r4[q], hv = h4[q];
      p += rv.x * hv.x + rv.y * hv.y + rv.z * hv.z + rv.w * hv.w;
    }
#pragma unroll
    for (int off = 32; off; off >>= 1) p += __shfl_xor(p, off);
    if (lane == 0) sc[s] = p;
  }
  __syncthreads();
  if (wave == 0) {
    float a = sc[lane], b2 = sc[64 + lane];
    float m = fmaxf(a, b2);
#pragma unroll
    for (int off = 32; off; off >>= 1) m = fmaxf(m, __shfl_xor(m, off));
    float ea = __expf(a - m), eb = __expf(b2 - m);
    float ss = ea + eb;
#pragma unroll
    for (int off = 32; off; off >>= 1) ss += __shfl_xor(ss, off);
    float inv = 1.0f / ss;
    sc[lane] = ea * inv;
    sc[64 + lane] = eb * inv;
  }
  __syncthreads();
  // ctx partials: lane owns j = lane*16..lane*16+15
  float a0[16];
#pragma unroll
  for (int q = 0; q < 16; ++q) a0[q] = 0.f;
  for (int i = 0; i < 32; ++i) {
    int s = wave * 32 + i;
    float wgt = sc[s];
    const float* row = enc_out + ((size_t)s * Bn + bb) * Hn + lane * 16;
#pragma unroll
    for (int q = 0; q < 16; q += 4) {
      float4 rv = *(const float4*)(row + q);
      a0[q] += wgt * rv.x; a0[q + 1] += wgt * rv.y;
      a0[q + 2] += wgt * rv.z; a0[q + 3] += wgt * rv.w;
    }
  }
#pragma unroll
  for (int q = 0; q < 16; ++q) cpart[wave][lane * 16 + q] = a0[q];
  __syncthreads();
#pragma unroll
  for (int q = 0; q < 4; ++q) {
    int j = tid * 4 + q;
    float v = cpart[0][j] + cpart[1][j] + cpart[2][j] + cpart[3][j];
    ctx[(size_t)bb * Hn + j] = v;
    ctx_b[(size_t)bb * Hn + j] = f2bf(v);
  }
}

// ---------------- host ----------------
extern "C" void kernel_launch(void* const* d_in, const int* in_sizes, int n_in,
                              void* d_out, int out_size, void* d_ws, size_t ws_size,
                              hipStream_t stream) {
  const int* src = (const int*)d_in[0];
  const int* tgt = (const int*)d_in[1];
  const float* embed = (const float*)d_in[2];
  const float* Wih0 = (const float*)d_in[3];
  const float* Whh0 = (const float*)d_in[4];
  const float* bih0 = (const float*)d_in[5];
  const float* bhh0 = (const float*)d_in[6];
  const float* Wih1 = (const float*)d_in[7];
  const float* Whh1 = (const float*)d_in[8];
  const float* bih1 = (const float*)d_in[9];
  const float* bhh1 = (const float*)d_in[10];
  const float* dWih = (const float*)d_in[11];
  const float* dWhh = (const float*)d_in[12];
  const float* dbih = (const float*)d_in[13];
  const float* dbhh = (const float*)d_in[14];
  const float* fcW = (const float*)d_in[15];
  const float* fcb = (const float*)d_in[16];
  float* out = (float*)d_out;

  char* p = (char*)d_ws;
  auto alloc = [&](size_t bytes) {
    void* r = p;
    p += (bytes + 255) & ~(size_t)255;
    return r;
  };
  u16* Wih0_b = (u16*)alloc((size_t)G4 * En * 2);
  u16* Whh0_b = (u16*)alloc((size_t)G4 * Hn * 2);
  u16* Wih1_b = (u16*)alloc((size_t)G4 * Hn * 2);
  u16* Whh1_b = (u16*)alloc((size_t)G4 * Hn * 2);
  u16* dWih_b = (u16*)alloc((size_t)G4 * 1536 * 2);
  u16* dWhh_b = (u16*)alloc((size_t)G4 * Hn * 2);
  u16* fcW_b = (u16*)alloc((size_t)Vn * Hn * 2);
  u16* embA = (u16*)alloc((size_t)Sn * Bn * En * 2);
  u16* hs0_b = (u16*)alloc((size_t)Sn * Bn * Hn * 2);
  float* premix = (float*)alloc((size_t)Sn * Bn * G4 * 4);
  float* enc_out = (float*)alloc((size_t)Sn * Bn * Hn * 4);
  float* h = (float*)alloc((size_t)Bn * Hn * 4);
  float* c = (float*)alloc((size_t)Bn * Hn * 4);
  u16* hb0 = (u16*)alloc((size_t)Bn * Hn * 2);
  u16* hb1 = (u16*)alloc((size_t)Bn * Hn * 2);
  float* ctx = (float*)alloc((size_t)Bn * Hn * 4);
  u16* ctx_b = (u16*)alloc((size_t)Bn * Hn * 2);

  auto cvt = [&](const float* in, u16* o, size_t n) {
    int n8 = (int)(n / 8);
    cvt_bf16_kernel<<<(n8 + 255) / 256, 256, 0, stream>>>(in, o, n8);
  };
  cvt(Wih0, Wih0_b, (size_t)G4 * En);
  cvt(Whh0, Whh0_b, (size_t)G4 * Hn);
  cvt(Wih1, Wih1_b, (size_t)G4 * Hn);
  cvt(Whh1, Whh1_b, (size_t)G4 * Hn);
  cvt(dWih, dWih_b, (size_t)G4 * 1536);
  cvt(dWhh, dWhh_b, (size_t)G4 * Hn);
  cvt(fcW, fcW_b, (size_t)Vn * Hn);

  // ---- encoder layer 0 ----
  {
    int nrows = Sn * Bn;  // 4096
    int total = nrows * (En / 8);
    gather_embed_kernel<<<(total + 255) / 256, 256, 0, stream>>>(src, Sn, embed, embA, nrows);
    // X0 = embA @ Wih0^T + bih0 + bhh0
    int Mtiles = nrows / 16, Ntiles = G4 / 16;
    gemm_bias_kernel<<<Mtiles * Ntiles / 4, 256, 0, stream>>>(embA, En, Wih0_b, En, bih0, bhh0,
                                                              premix, G4, Mtiles, En);
  }
  (void)hipMemsetAsync(h, 0, (size_t)Bn * Hn * 4, stream);
  (void)hipMemsetAsync(c, 0, (size_t)Bn * Hn * 4, stream);
  (void)hipMemsetAsync(hb0, 0, (size_t)Bn * Hn * 2, stream);
  u16 *hin = hb0, *hout = hb1;
  for (int t = 0; t < Sn; ++t) {
    lstm_step_kernel<<<128, 256, 0, stream>>>(premix + (size_t)t * Bn * G4, Whh0_b, hin, h, c, hout,
                                              hs0_b + (size_t)t * Bn * Hn, nullptr);
    u16* tmp = hin; hin = hout; hout = tmp;
  }
  // ---- encoder layer 1 ----
  {
    int Mtiles = (Sn * Bn) / 16, Ntiles = G4 / 16;
    gemm_bias_kernel<<<Mtiles * Ntiles / 4, 256, 0, stream>>>(hs0_b, Hn, Wih1_b, Hn, bih1, bhh1,
                                                              premix, G4, Mtiles, Hn);
  }
  (void)hipMemsetAsync(h, 0, (size_t)Bn * Hn * 4, stream);
  (void)hipMemsetAsync(c, 0, (size_t)Bn * Hn * 4, stream);
  (void)hipMemsetAsync(hin, 0, (size_t)Bn * Hn * 2, stream);
  for (int t = 0; t < Sn; ++t) {
    lstm_step_kernel<<<128, 256, 0, stream>>>(premix + (size_t)t * Bn * G4, Whh1_b, hin, h, c, hout,
                                              nullptr, enc_out + (size_t)t * Bn * Hn);
    u16* tmp = hin; hin = hout; hout = tmp;
  }
  // ---- decoder premix: Xd = dec_emb @ dWih[:, :E]^T + dbih + dbhh ----
  {
    int nrows = Td * Bn;  // 4064
    int total = nrows * (En / 8);
    gather_embed_kernel<<<(total + 255) / 256, 256, 0, stream>>>(tgt, Sn, embed, embA, nrows);
    int Mtiles = nrows / 16, Ntiles = G4 / 16;
    gemm_bias_kernel<<<Mtiles * Ntiles / 4, 256, 0, stream>>>(embA, En, dWih_b, 1536, dbih, dbhh,
                                                              premix, G4, Mtiles, En);
  }
  // ---- decoder ----
  // prologue: attention for t=0 from h_last
  fc_attn_kernel<<<32, 256, 0, stream>>>(hin, h, fcW_b, fcb, out, enc_out, ctx, ctx_b, 0, 0);
  for (int t = 0; t < Td; ++t) {
    dec_step_kernel<<<128, 256, 0, stream>>>(premix + (size_t)t * Bn * G4, dWih_b + 512, dWhh_b,
                                             ctx_b, hin, h, c, hout);
    u16* tmp = hin; hin = hout; hout = tmp;
    int nattn = (t < Td - 1) ? 32 : 0;
    fc_attn_kernel<<<500 + nattn, 256, 0, stream>>>(hin, h, fcW_b, fcb, out, enc_out, ctx, ctx_b, t,
                                                    500);
  }
}

// Round 2
// 7160.255 us; speedup vs baseline: 1.5447x; 1.5447x over previous
//
#include <hip/hip_runtime.h>

// ---------------- types / helpers ----------------
typedef unsigned short u16;
typedef __bf16 bf16x8 __attribute__((ext_vector_type(8)));
typedef float f32x4 __attribute__((ext_vector_type(4)));
typedef u16 u16x8 __attribute__((ext_vector_type(8)));

static_assert(sizeof(bf16x8) == 16, "bf16x8 must be 16B");

#define DEV static __device__ __forceinline__

DEV u16 f2bf(float f) {
  unsigned u = __float_as_uint(f);
  u += 0x7FFFu + ((u >> 16) & 1u);   // RNE; inputs are well-behaved (no NaN/Inf)
  return (u16)(u >> 16);
}
DEV float bf2f(u16 h) { return __uint_as_float(((unsigned)h) << 16); }
DEV f32x4 mfma16(bf16x8 a, bf16x8 b, f32x4 c) {
  return __builtin_amdgcn_mfma_f32_16x16x32_bf16(a, b, c, 0, 0, 0);
}
DEV bf16x8 ldfrag(const u16* p) { return *reinterpret_cast<const bf16x8*>(p); }
DEV float sigf(float x) { return 1.0f / (1.0f + __expf(-x)); }
DEV void gld16(const void* g, void* l) {
  __builtin_amdgcn_global_load_lds((const __attribute__((address_space(1))) void*)g,
                                   (__attribute__((address_space(3))) void*)l, 16, 0, 0);
}

// dims
#define Bn 32
#define Sn 128
#define Td 127
#define En 512
#define Hn 1024
#define G4 4096
#define Vn 32000

// ---------------- f32 -> bf16 convert ----------------
__global__ __launch_bounds__(256) void cvt_bf16_kernel(const float* __restrict__ in,
                                                       u16* __restrict__ out, int n8) {
  int gid = blockIdx.x * 256 + threadIdx.x;
  if (gid >= n8) return;
  const float4* ip = (const float4*)in + gid * 2;
  float4 x = ip[0], y = ip[1];
  u16x8 o;
  o[0] = f2bf(x.x); o[1] = f2bf(x.y); o[2] = f2bf(x.z); o[3] = f2bf(x.w);
  o[4] = f2bf(y.x); o[5] = f2bf(y.y); o[6] = f2bf(y.z); o[7] = f2bf(y.w);
  ((u16x8*)out)[gid] = o;
}

// ---------------- embedding gather (to bf16, (t*B+b, E) layout) ----------------
__global__ __launch_bounds__(256) void gather_embed_kernel(const int* __restrict__ idx, int ldidx,
                                                           const float* __restrict__ embed,
                                                           u16* __restrict__ outA, int nrows) {
  int gid = blockIdx.x * 256 + threadIdx.x;          // one thread = 8 elems
  int total = nrows * (En / 8);
  if (gid >= total) return;
  int r = gid / (En / 8);
  int ck = gid % (En / 8);
  int tcol = r / Bn, b = r % Bn;
  int tok = idx[b * ldidx + tcol];
  const float4* src = (const float4*)(embed + (size_t)tok * En + ck * 8);
  float4 x = src[0], y = src[1];
  u16x8 o;
  o[0] = f2bf(x.x); o[1] = f2bf(x.y); o[2] = f2bf(x.z); o[3] = f2bf(x.w);
  o[4] = f2bf(y.x); o[5] = f2bf(y.y); o[6] = f2bf(y.z); o[7] = f2bf(y.w);
  *(u16x8*)(outA + (size_t)r * En + ck * 8) = o;
}

// ---------------- tiled GEMM (m97-style 128x128, BK=32, global_load_lds) ----------------
// C(M,N) = A(M,K) @ W(N,K)^T (+bias). mode0: C row-major f32 (+bias0+bias1).
// mode1: fc epilogue -> out[(b*Td+t)*Vn+n] = acc + bias0[n], rows m = t*32+b, skip m>=Td*Bn.
__global__ __launch_bounds__(256) void gemm_tile_kernel(const u16* __restrict__ A, int lda,
                                                        const u16* __restrict__ W, int ldw,
                                                        const float* __restrict__ bias0,
                                                        const float* __restrict__ bias1,
                                                        float* __restrict__ Cout, int ldc,
                                                        int Mtiles, int K, int mode) {
  __shared__ u16 Asb[128 * 32];
  __shared__ u16 Bsb[128 * 32];
  int nwg = gridDim.x;
  int cpx = nwg >> 3;
  int bid = ((int)blockIdx.x & 7) * cpx + ((int)blockIdx.x >> 3);  // XCD swizzle (nwg%8==0)
  int mt = bid % Mtiles, nt = bid / Mtiles;
  int tid = threadIdx.x;
  int wave = tid >> 6, lane = tid & 63;
  int lrow = lane & 15, kgrp = lane >> 4;
  int wr = wave >> 1, wc = wave & 1;
  // staging: wave w issues 2 chunks of 1KB; lane elem index e = w*1024 + lane*8 (+512)
  int e0 = wave * 1024 + lane * 8;
  int r0 = e0 >> 5, c0 = e0 & 31;
  int r1 = r0 + 16;
  const u16* Ab = A + (size_t)(mt * 128) * lda;
  const u16* Wb = W + (size_t)(nt * 128) * ldw;
  u16* AsW = Asb + wave * 1024;
  u16* BsW = Bsb + wave * 1024;
  f32x4 acc[4][4] = {};
  for (int k0 = 0; k0 < K; k0 += 32) {
    gld16(Ab + (size_t)r0 * lda + k0 + c0, AsW);
    gld16(Ab + (size_t)r1 * lda + k0 + c0, AsW + 512);
    gld16(Wb + (size_t)r0 * ldw + k0 + c0, BsW);
    gld16(Wb + (size_t)r1 * ldw + k0 + c0, BsW + 512);
    __syncthreads();
    bf16x8 af[4], bfr[4];
#pragma unroll
    for (int i = 0; i < 4; ++i) af[i] = ldfrag(Asb + (wr * 64 + i * 16 + lrow) * 32 + kgrp * 8);
#pragma unroll
    for (int i = 0; i < 4; ++i) bfr[i] = ldfrag(Bsb + (wc * 64 + i * 16 + lrow) * 32 + kgrp * 8);
#pragma unroll
    for (int i = 0; i < 4; ++i)
#pragma unroll
      for (int j = 0; j < 4; ++j) acc[i][j] = mfma16(af[i], bfr[j], acc[i][j]);
    __syncthreads();
  }
  if (mode == 0) {
#pragma unroll
    for (int i = 0; i < 4; ++i) {
      int m = mt * 128 + wr * 64 + i * 16 + kgrp * 4;
#pragma unroll
      for (int j = 0; j < 4; ++j) {
        int n = nt * 128 + wc * 64 + j * 16 + lrow;
        float bb = (bias0 ? bias0[n] : 0.f) + (bias1 ? bias1[n] : 0.f);
#pragma unroll
        for (int r = 0; r < 4; ++r) Cout[(size_t)(m + r) * ldc + n] = acc[i][j][r] + bb;
      }
    }
  } else {
#pragma unroll
    for (int i = 0; i < 4; ++i) {
      int m = mt * 128 + wr * 64 + i * 16 + kgrp * 4;
#pragma unroll
      for (int j = 0; j < 4; ++j) {
        int n = nt * 128 + wc * 64 + j * 16 + lrow;
        float bb = bias0[n];
#pragma unroll
        for (int r = 0; r < 4; ++r) {
          int mm = m + r;
          if (mm < Td * Bn) {
            int tt = mm >> 5, b = mm & 31;
            Cout[((size_t)b * Td + tt) * Vn + n] = acc[i][j][r] + bb;
          }
        }
      }
    }
  }
}

// ---------------- LSTM step building blocks ----------------
// one block: mt (16 batch rows), ht (16 h cols), 4 gates. 4 waves split K (256 each of 1024).
DEV void gemm4_part(const u16* __restrict__ A /*32xHn*/, const u16* __restrict__ Wm, int ldw,
                    int mt, int ht, int wave, int lrow, int kgrp, f32x4 acc[4]) {
  const int kb = wave * 256;
  const u16* ar = A + (size_t)(mt * 16 + lrow) * Hn;
  const u16* wr0 = Wm + (size_t)(ht * 16 + lrow) * ldw;
#pragma unroll 2
  for (int kk = 0; kk < 8; ++kk) {
    int k0 = kb + kk * 32 + kgrp * 8;
    bf16x8 a = ldfrag(ar + k0);
#pragma unroll
    for (int g = 0; g < 4; ++g) {
      bf16x8 b = ldfrag(wr0 + (size_t)g * Hn * ldw + k0);
      acc[g] = mfma16(a, b, acc[g]);
    }
  }
}

DEV void lstm_tail(float lds[4][4][16][16], f32x4 acc[4], int wave, int lrow, int kgrp,
                   int mt, int ht, int tid,
                   const float* __restrict__ pm_t,                        // premix row base or null
                   const float* __restrict__ b0, const float* __restrict__ b1,  // bias pair or null
                   float* __restrict__ c, u16* __restrict__ hb_w,
                   u16* __restrict__ extra_b) {
#pragma unroll
  for (int g = 0; g < 4; ++g)
#pragma unroll
    for (int r = 0; r < 4; ++r) lds[wave][g][kgrp * 4 + r][lrow] = acc[g][r];
  __syncthreads();
  int row = tid >> 4, col = tid & 15;
  int brow = mt * 16 + row, hcol = ht * 16 + col;
  float gs[4];
#pragma unroll
  for (int g = 0; g < 4; ++g) {
    float s = lds[0][g][row][col] + lds[1][g][row][col] + lds[2][g][row][col] + lds[3][g][row][col];
    if (pm_t) s += pm_t[(size_t)brow * G4 + g * Hn + hcol];
    if (b0) s += b0[g * Hn + hcol] + b1[g * Hn + hcol];
    gs[g] = s;
  }
  float cold = c[brow * Hn + hcol];
  float ig = sigf(gs[0]), fg = sigf(gs[1]), gg = tanhf(gs[2]), og = sigf(gs[3]);
  float cn = fg * cold + ig * gg;
  float hn = og * tanhf(cn);
  c[brow * Hn + hcol] = cn;
  u16 hb = f2bf(hn);
  hb_w[brow * Hn + hcol] = hb;
  if (extra_b) extra_b[brow * Hn + hcol] = hb;
}

// ---------------- fused encoder pair: layer0 step t  ||  layer1 step t-1 ----------------
__global__ __launch_bounds__(256) void enc_pair_kernel(
    int t, const float* __restrict__ premix, const u16* __restrict__ Whh0,
    const u16* __restrict__ hb0_r, u16* __restrict__ hb0_w, float* __restrict__ c0,
    const u16* __restrict__ Wih1, const u16* __restrict__ Whh1,
    const float* __restrict__ bih1, const float* __restrict__ bhh1,
    const u16* __restrict__ hb1_r, u16* __restrict__ hb1_w, float* __restrict__ c1,
    u16* __restrict__ enc_b) {
  __shared__ float lds[4][4][16][16];
  const int wave = threadIdx.x >> 6, lane = threadIdx.x & 63;
  const int lrow = lane & 15, kgrp = lane >> 4;
  int blk = blockIdx.x;
  if (blk < 128) {
    if (t >= Sn) return;
    int mt = blk & 1, ht = blk >> 1;
    f32x4 acc[4] = {};
    gemm4_part(hb0_r, Whh0, Hn, mt, ht, wave, lrow, kgrp, acc);
    lstm_tail(lds, acc, wave, lrow, kgrp, mt, ht, threadIdx.x,
              premix + (size_t)t * Bn * G4, nullptr, nullptr, c0, hb0_w, nullptr);
  } else {
    if (t < 1) return;
    int bb = blk - 128;
    int mt = bb & 1, ht = bb >> 1;
    f32x4 acc[4] = {};
    gemm4_part(hb0_r, Wih1, Hn, mt, ht, wave, lrow, kgrp, acc);  // hs0(t-1) @ Wih1^T
    gemm4_part(hb1_r, Whh1, Hn, mt, ht, wave, lrow, kgrp, acc);  // h1(t-2) @ Whh1^T
    lstm_tail(lds, acc, wave, lrow, kgrp, mt, ht, threadIdx.x, nullptr, bih1, bhh1, c1, hb1_w,
              enc_b + (size_t)(t - 1) * Bn * Hn);
  }
}

// ---------------- decoder LSTM step ----------------
__global__ __launch_bounds__(256) void dec_step_kernel(
    const float* __restrict__ pm_t, const u16* __restrict__ Wih_ctx, const u16* __restrict__ Whh,
    const u16* __restrict__ ctx_b, const u16* __restrict__ hb_r, float* __restrict__ c,
    u16* __restrict__ hb_w, u16* __restrict__ hs_t) {
  __shared__ float lds[4][4][16][16];
  const int wave = threadIdx.x >> 6, lane = threadIdx.x & 63;
  const int lrow = lane & 15, kgrp = lane >> 4;
  int mt = blockIdx.x & 1, ht = blockIdx.x >> 1;
  f32x4 acc[4] = {};
  gemm4_part(ctx_b, Wih_ctx, 1536, mt, ht, wave, lrow, kgrp, acc);
  gemm4_part(hb_r, Whh, Hn, mt, ht, wave, lrow, kgrp, acc);
  lstm_tail(lds, acc, wave, lrow, kgrp, mt, ht, threadIdx.x, pm_t, nullptr, nullptr, c, hb_w, hs_t);
}

// ---------------- attention (bf16 enc_out, h kept in registers) ----------------
__global__ __launch_bounds__(256) void attn_kernel(const u16* __restrict__ hq,
                                                   const u16* __restrict__ enc_b,
                                                   u16* __restrict__ ctx_b) {
  __shared__ float sc[Sn];
  __shared__ float cpart[4][16][64];
  int bb = blockIdx.x;
  int wave = threadIdx.x >> 6, lane = threadIdx.x & 63;
  float hreg[16];
  {
    const u16x8* hp = (const u16x8*)(hq + (size_t)bb * Hn + lane * 16);
    u16x8 h0 = hp[0], h1 = hp[1];
#pragma unroll
    for (int q = 0; q < 8; ++q) { hreg[q] = bf2f(h0[q]); hreg[8 + q] = bf2f(h1[q]); }
  }
  for (int i = 0; i < 32; ++i) {
    int s = wave * 32 + i;
    const u16x8* rp = (const u16x8*)(enc_b + ((size_t)s * Bn + bb) * Hn + lane * 16);
    u16x8 v0 = rp[0], v1 = rp[1];
    float p = 0.f;
#pragma unroll
    for (int q = 0; q < 8; ++q) p += bf2f(v0[q]) * hreg[q] + bf2f(v1[q]) * hreg[8 + q];
#pragma unroll
    for (int off = 32; off; off >>= 1) p += __shfl_xor(p, off);
    if (lane == 0) sc[s] = p;
  }
  __syncthreads();
  if (wave == 0) {
    float a = sc[lane], b2 = sc[64 + lane];
    float m = fmaxf(a, b2);
#pragma unroll
    for (int off = 32; off; off >>= 1) m = fmaxf(m, __shfl_xor(m, off));
    float ea = __expf(a - m), eb = __expf(b2 - m);
    float ss = ea + eb;
#pragma unroll
    for (int off = 32; off; off >>= 1) ss += __shfl_xor(ss, off);
    float inv = 1.0f / ss;
    sc[lane] = ea * inv;
    sc[64 + lane] = eb * inv;
  }
  __syncthreads();
  float a0[16];
#pragma unroll
  for (int q = 0; q < 16; ++q) a0[q] = 0.f;
  for (int i = 0; i < 32; ++i) {
    int s = wave * 32 + i;
    float wgt = sc[s];
    const u16x8* rp = (const u16x8*)(enc_b + ((size_t)s * Bn + bb) * Hn + lane * 16);
    u16x8 v0 = rp[0], v1 = rp[1];
#pragma unroll
    for (int q = 0; q < 8; ++q) { a0[q] += wgt * bf2f(v0[q]); a0[8 + q] += wgt * bf2f(v1[q]); }
  }
#pragma unroll
  for (int q = 0; q < 16; ++q) cpart[wave][q][lane] = a0[q];  // transposed: conflict-free
  __syncthreads();
  int tid = threadIdx.x;
#pragma unroll
  for (int q = 0; q < 4; ++q) {
    int j = tid * 4 + q;
    float v = cpart[0][j & 15][j >> 4] + cpart[1][j & 15][j >> 4] + cpart[2][j & 15][j >> 4] +
              cpart[3][j & 15][j >> 4];
    ctx_b[(size_t)bb * Hn + j] = f2bf(v);
  }
}

// ---------------- host ----------------
extern "C" void kernel_launch(void* const* d_in, const int* in_sizes, int n_in,
                              void* d_out, int out_size, void* d_ws, size_t ws_size,
                              hipStream_t stream) {
  const int* src = (const int*)d_in[0];
  const int* tgt = (const int*)d_in[1];
  const float* embed = (const float*)d_in[2];
  const float* Wih0 = (const float*)d_in[3];
  const float* Whh0 = (const float*)d_in[4];
  const float* bih0 = (const float*)d_in[5];
  const float* bhh0 = (const float*)d_in[6];
  const float* Wih1 = (const float*)d_in[7];
  const float* Whh1 = (const float*)d_in[8];
  const float* bih1 = (const float*)d_in[9];
  const float* bhh1 = (const float*)d_in[10];
  const float* dWih = (const float*)d_in[11];
  const float* dWhh = (const float*)d_in[12];
  const float* dbih = (const float*)d_in[13];
  const float* dbhh = (const float*)d_in[14];
  const float* fcW = (const float*)d_in[15];
  const float* fcb = (const float*)d_in[16];
  float* out = (float*)d_out;

  char* p = (char*)d_ws;
  auto alloc = [&](size_t bytes) {
    void* r = p;
    p += (bytes + 255) & ~(size_t)255;
    return r;
  };
  u16* Wih0_b = (u16*)alloc((size_t)G4 * En * 2);
  u16* Whh0_b = (u16*)alloc((size_t)G4 * Hn * 2);
  u16* Wih1_b = (u16*)alloc((size_t)G4 * Hn * 2);
  u16* Whh1_b = (u16*)alloc((size_t)G4 * Hn * 2);
  u16* dWih_b = (u16*)alloc((size_t)G4 * 1536 * 2);
  u16* dWhh_b = (u16*)alloc((size_t)G4 * Hn * 2);
  u16* fcW_b = (u16*)alloc((size_t)Vn * Hn * 2);
  u16* embA = (u16*)alloc((size_t)4096 * En * 2);
  float* premix = (float*)alloc((size_t)4096 * G4 * 4);       // reused: enc l0, then decoder
  u16* enc_b = (u16*)alloc((size_t)Sn * Bn * Hn * 2);
  u16* hs_dec = (u16*)alloc((size_t)4096 * Hn * 2);           // rows t*32+b; tail zeroed
  float* c0 = (float*)alloc((size_t)Bn * Hn * 4);
  float* c1 = (float*)alloc((size_t)Bn * Hn * 4);
  u16* hb0a = (u16*)alloc((size_t)Bn * Hn * 2);
  u16* hb0b = (u16*)alloc((size_t)Bn * Hn * 2);
  u16* hb1a = (u16*)alloc((size_t)Bn * Hn * 2);
  u16* hb1b = (u16*)alloc((size_t)Bn * Hn * 2);
  u16* ctx_b = (u16*)alloc((size_t)Bn * Hn * 2);
  u16* H0[2] = {hb0a, hb0b};
  u16* H1[2] = {hb1a, hb1b};

  auto cvt = [&](const float* in, u16* o, size_t n) {
    int n8 = (int)(n / 8);
    cvt_bf16_kernel<<<(n8 + 255) / 256, 256, 0, stream>>>(in, o, n8);
  };
  cvt(Wih0, Wih0_b, (size_t)G4 * En);
  cvt(Whh0, Whh0_b, (size_t)G4 * Hn);
  cvt(Wih1, Wih1_b, (size_t)G4 * Hn);
  cvt(Whh1, Whh1_b, (size_t)G4 * Hn);
  cvt(dWih, dWih_b, (size_t)G4 * 1536);
  cvt(dWhh, dWhh_b, (size_t)G4 * Hn);
  cvt(fcW, fcW_b, (size_t)Vn * Hn);

  // ---- encoder premix (layer0 input projection, all t at once) ----
  {
    int total = 4096 * (En / 8);
    gather_embed_kernel<<<(total + 255) / 256, 256, 0, stream>>>(src, Sn, embed, embA, Sn * Bn);
    gemm_tile_kernel<<<32 * 32, 256, 0, stream>>>(embA, En, Wih0_b, En, bih0, bhh0, premix, G4,
                                                  32, En, 0);
  }
  (void)hipMemsetAsync(c0, 0, (size_t)Bn * Hn * 4, stream);
  (void)hipMemsetAsync(c1, 0, (size_t)Bn * Hn * 4, stream);
  (void)hipMemsetAsync(hb0a, 0, (size_t)Bn * Hn * 2, stream);
  (void)hipMemsetAsync(hb1a, 0, (size_t)Bn * Hn * 2, stream);
  (void)hipMemsetAsync(hs_dec + (size_t)(Td * Bn) * Hn, 0,
                       (size_t)(4096 - Td * Bn) * Hn * 2, stream);  // GEMM tail rows

  // ---- fused encoder: layer0 step t || layer1 step t-1 ----
  for (int t = 0; t <= Sn; ++t) {
    enc_pair_kernel<<<256, 256, 0, stream>>>(t, premix, Whh0_b,
                                             H0[t & 1], H0[(t + 1) & 1], c0,
                                             Wih1_b, Whh1_b, bih1, bhh1,
                                             H1[(t + 1) & 1], H1[t & 1], c1, enc_b);
  }
  // h1 final now in H1[0]; c1 holds c_last; decoder continues with them.

  // ---- decoder premix: Xd = dec_emb @ dWih[:, :E]^T + dbih + dbhh ----
  {
    int nrows = Td * Bn;  // 4064 (tail tiles computed on stale embA rows, never read)
    int total = nrows * (En / 8);
    gather_embed_kernel<<<(total + 255) / 256, 256, 0, stream>>>(tgt, Sn, embed, embA, nrows);
    gemm_tile_kernel<<<32 * 32, 256, 0, stream>>>(embA, En, dWih_b, 1536, dbih, dbhh, premix, G4,
                                                  32, En, 0);
  }

  // ---- decoder loop: attention(t) then LSTM step(t); fc batched at the end ----
  for (int t = 0; t < Td; ++t) {
    attn_kernel<<<32, 256, 0, stream>>>(H1[t & 1], enc_b, ctx_b);
    dec_step_kernel<<<128, 256, 0, stream>>>(premix + (size_t)t * Bn * G4, dWih_b + 512, dWhh_b,
                                             ctx_b, H1[t & 1], c1, H1[(t + 1) & 1],
                                             hs_dec + (size_t)t * Bn * Hn);
  }

  // ---- batched fc: out = hs_dec @ fc_W^T + fc_b (M=4096 incl. zero tail, N=32000, K=1024) ----
  gemm_tile_kernel<<<32 * 250, 256, 0, stream>>>(hs_dec, Hn, fcW_b, Hn, fcb, nullptr, out, 0,
                                                 32, Hn, 1);
}